// Round 2
// baseline (255.029 us; speedup 1.0000x reference)
//
#include <hip/hip_runtime.h>

typedef unsigned short ushort;
typedef __attribute__((ext_vector_type(8))) short bf16x8;
typedef __attribute__((ext_vector_type(4))) float f32x4;
typedef __attribute__((ext_vector_type(4))) ushort us4;

#define NBATCH 32
#define ICN 256
#define OCN 256
#define HSZ 56
#define WSZ 56
#define HP 58
#define SPAT (HP*HP)            /* 3364 */
#define KTOT 2304               /* 9*256, k = (kh*3+kw)*256 + ic */
#define MTOT (NBATCH*HSZ*WSZ)   /* 100352 */

#define XP_BYTES ((size_t)NBATCH*SPAT*ICN*2)   /* 55,115,776 */
#define WD_BYTES ((size_t)OCN*KTOT*4)          /* 2,359,296  */

__device__ __forceinline__ ushort f2bf(float f) {
  union { float f; unsigned u; } c; c.f = f;
  unsigned r = c.u + 0x7FFFu + ((c.u >> 16) & 1u);
  return (ushort)(r >> 16);
}

// x [N][IC][56][56] f32 -> xp [N][58][58][IC] bf16 (interior only; halo stays 0)
__global__ void k_transpose(const float* __restrict__ x, ushort* __restrict__ xp) {
  __shared__ float tile[ICN*57];   // stride 57: gcd(57,32)=1 -> conflict-free transpose read
  int h = blockIdx.x, n = blockIdx.y;
  const float* src = x + ((size_t)n*ICN*HSZ*WSZ) + h*WSZ;
  for (int e = threadIdx.x; e < ICN*WSZ; e += 256) {
    int ic = e / WSZ, w = e - ic*WSZ;                 // w fastest -> coalesced global read
    tile[ic*57 + w] = src[ic*(HSZ*WSZ) + w];
  }
  __syncthreads();
  ushort* dst = xp + ((size_t)n*SPAT + (size_t)(h+1)*HP + 1)*ICN;
  for (int e = threadIdx.x; e < ICN*WSZ; e += 256) {
    int w = e >> 8, ic = e & 255;                     // ic fastest -> coalesced bf16 write
    dst[w*ICN + ic] = f2bf(tile[ic*57 + w]);
  }
}

// COO scatter into dense fp32 W [oc][k], duplicates sum via atomicAdd
__global__ void k_scatter(const int* __restrict__ idx, const float* __restrict__ val,
                          float* __restrict__ wd, int nnz) {
  int i = blockIdx.x*256 + threadIdx.x;
  if (i >= nnz) return;
  int id = idx[i];
  int oc = id / (ICN*9);
  int rem = id - oc*(ICN*9);
  int ic = rem / 9;
  int k9 = rem - ic*9;                                // kh*3+kw
  atomicAdd(wd + (size_t)oc*KTOT + k9*ICN + ic, val[i]);
}

__global__ void k_convert(const float* __restrict__ wd, ushort* __restrict__ bm) {
  int i = (blockIdx.x*256 + threadIdx.x)*4;
  float4 v = *(const float4*)(wd + i);
  us4 o; o[0]=f2bf(v.x); o[1]=f2bf(v.y); o[2]=f2bf(v.z); o[3]=f2bf(v.w);
  *(us4*)(bm + i) = o;
}

// Implicit-GEMM: out[m][oc] = sum_k A[m][k]*B[oc][k],  A from xp (im2col), B = bm.
// 128x128 tile, BK=32, 4 waves (2x2, 64x64 each), 16x16x32 bf16 MFMA, dbuf LDS.
__global__ __launch_bounds__(256) void k_gemm(const ushort* __restrict__ xp,
                                              const ushort* __restrict__ bm,
                                              const float* __restrict__ bias,
                                              float* __restrict__ out) {
  __shared__ __align__(16) ushort Ab[2][128*32];
  __shared__ __align__(16) ushort Bb[2][128*32];
  const int tid = threadIdx.x;
  const int lam = tid & 63;
  const int wv  = tid >> 6;
  const int wr = wv >> 1, wc = wv & 1;
  const int m0  = blockIdx.x * 128;
  const int oc0 = blockIdx.y * 128;

  // Staging: per wave-instr, gld_lds writes LDS linearly (base + lane*16B).
  // LDS slot (row r, quad p) holds logical k-octet kq = p ^ (r&3)  (T2 swizzle,
  // applied by pre-swizzling the GLOBAL source address; LDS dest stays linear).
  int srcA[2], srcB[2], ldsOff[2];
#pragma unroll
  for (int i = 0; i < 2; ++i) {
    int slot = (wv*2 + i)*64 + lam;      // 16B-slot index in 8KB tile
    int r  = slot >> 2;                  // tile row 0..127 (64B rows)
    int kq = (slot & 3) ^ (r & 3);       // logical k-octet for this slot
    ldsOff[i] = (wv*2 + i)*512;          // ushort offset of wave-uniform dest
    int m = m0 + r;
    int n = m / 3136;
    int rem = m - n*3136;
    int oh = rem / 56;
    int ow = rem - oh*56;
    srcA[i] = (n*SPAT + oh*HP + ow)*ICN + kq*8;   // + ((kh*58+kw)<<8) + ic0 per step
    srcB[i] = (oc0 + r)*KTOT + kq*8;              // + s*32 per step
  }
  // Fragment ds_read_b128 offsets (same XOR on read side)
  int aoff[4], boff[4];
#pragma unroll
  for (int f = 0; f < 4; ++f) {
    int ra = wr*64 + f*16 + (lam & 15);
    aoff[f] = ra*64 + (((lam>>4) ^ (ra&3)) << 4);
    int rb = wc*64 + f*16 + (lam & 15);
    boff[f] = rb*64 + (((lam>>4) ^ (rb&3)) << 4);
  }

  f32x4 acc[4][4];
#pragma unroll
  for (int a = 0; a < 4; ++a)
#pragma unroll
    for (int b = 0; b < 4; ++b) acc[a][b] = (f32x4){0.f, 0.f, 0.f, 0.f};

  const int NS = KTOT/32;  // 72

  // prologue: stage K-step 0 into buf 0
#pragma unroll
  for (int i = 0; i < 2; ++i) {
    __builtin_amdgcn_global_load_lds((const __attribute__((address_space(1))) void*)(xp + srcA[i]),
        (__attribute__((address_space(3))) void*)(&Ab[0][ldsOff[i]]), 16, 0, 0);
    __builtin_amdgcn_global_load_lds((const __attribute__((address_space(1))) void*)(bm + srcB[i]),
        (__attribute__((address_space(3))) void*)(&Bb[0][ldsOff[i]]), 16, 0, 0);
  }
  asm volatile("s_waitcnt vmcnt(0)" ::: "memory");
  __syncthreads();

  for (int s = 0; s < NS; ++s) {
    const int cur = s & 1;
    if (s + 1 < NS) {                     // issue next-tile loads BEFORE compute
      const int s1 = s + 1;
      const int t  = s1 >> 3;             // (kh,kw) chunk: BK=32 never crosses ic=256
      const int kh = t / 3, kw = t - kh*3;
      const int shA = ((kh*HP + kw) << 8) + ((s1 & 7) << 5);
      const int shB = s1 << 5;
#pragma unroll
      for (int i = 0; i < 2; ++i) {
        __builtin_amdgcn_global_load_lds((const __attribute__((address_space(1))) void*)(xp + srcA[i] + shA),
            (__attribute__((address_space(3))) void*)(&Ab[cur^1][ldsOff[i]]), 16, 0, 0);
        __builtin_amdgcn_global_load_lds((const __attribute__((address_space(1))) void*)(bm + srcB[i] + shB),
            (__attribute__((address_space(3))) void*)(&Bb[cur^1][ldsOff[i]]), 16, 0, 0);
      }
    }
    bf16x8 av[4], bv[4];
#pragma unroll
    for (int f = 0; f < 4; ++f) av[f] = *(const bf16x8*)((const char*)(&Ab[cur][0]) + aoff[f]);
#pragma unroll
    for (int f = 0; f < 4; ++f) bv[f] = *(const bf16x8*)((const char*)(&Bb[cur][0]) + boff[f]);
#pragma unroll
    for (int mi = 0; mi < 4; ++mi)
#pragma unroll
      for (int ni = 0; ni < 4; ++ni)
        acc[mi][ni] = __builtin_amdgcn_mfma_f32_16x16x32_bf16(av[mi], bv[ni], acc[mi][ni], 0, 0, 0);
    __syncthreads();   // compiler emits vmcnt(0) lgkmcnt(0) drain here
  }

  // epilogue: D frag lane l: col(oc)=l&15, row(m)=(l>>4)*4+j ; 4 regs = 4 consecutive m
#pragma unroll
  for (int ni = 0; ni < 4; ++ni) {
    int oc = oc0 + wc*64 + ni*16 + (lam & 15);
    float bvs = bias[oc];
#pragma unroll
    for (int mi = 0; mi < 4; ++mi) {
      int m = m0 + wr*64 + mi*16 + ((lam >> 4) << 2);
      int n = m / 3136;
      int rem = m - n*3136;     // never straddles n within a float4 (3136 % 4 == 0)
      float4 o;
      o.x = acc[mi][ni][0] + bvs;
      o.y = acc[mi][ni][1] + bvs;
      o.z = acc[mi][ni][2] + bvs;
      o.w = acc[mi][ni][3] + bvs;
      *(float4*)(out + ((size_t)(n*OCN + oc))*3136 + rem) = o;
    }
  }
}

extern "C" void kernel_launch(void* const* d_in, const int* in_sizes, int n_in,
                              void* d_out, int out_size, void* d_ws, size_t ws_size,
                              hipStream_t stream) {
  const float* x    = (const float*)d_in[0];
  const float* wval = (const float*)d_in[1];
  const int*   widx = (const int*)d_in[2];
  const float* bias = (const float*)d_in[3];
  float* out = (float*)d_out;
  const int nnz = in_sizes[1];

  char* ws = (char*)d_ws;
  ushort* xp = (ushort*)ws;                               // 55.1 MB
  float*  wd = (float*)(ws + XP_BYTES);                   // 2.36 MB
  ushort* bm = (ushort*)(ws + XP_BYTES + WD_BYTES);       // 1.18 MB

  hipMemsetAsync(xp, 0, XP_BYTES, stream);                // zero incl. halo
  hipMemsetAsync(wd, 0, WD_BYTES, stream);
  k_transpose<<<dim3(HSZ, NBATCH), 256, 0, stream>>>(x, xp);
  k_scatter<<<dim3((nnz + 255)/256), 256, 0, stream>>>(widx, wval, wd, nnz);
  k_convert<<<dim3((OCN*KTOT)/(256*4)), 256, 0, stream>>>(wd, bm);
  k_gemm<<<dim3(MTOT/128, OCN/128), 256, 0, stream>>>(xp, bm, bias, out);
}

// Round 3
// 226.937 us; speedup vs baseline: 1.1238x; 1.1238x over previous
//
#include <hip/hip_runtime.h>

typedef unsigned short ushort;
typedef __attribute__((ext_vector_type(8))) short bf16x8;
typedef __attribute__((ext_vector_type(4))) float f32x4;
typedef __attribute__((ext_vector_type(4))) ushort us4;

#define NBATCH 32
#define ICN 256
#define OCN 256
#define HSZ 56
#define WSZ 56
#define HP 58
#define SPAT (HP*HP)            /* 3364 */
#define KTOT 2304               /* 9*256, k = (kh*3+kw)*256 + ic */
#define MTOT (NBATCH*HSZ*WSZ)   /* 100352 */
#define NT   (KTOT/64)          /* 36 K-tiles of BK=64 */

#define XP_BYTES ((size_t)NBATCH*SPAT*ICN*2)   /* 55,115,776 */
#define WD_BYTES ((size_t)OCN*KTOT*4)          /* 2,359,296  */

__device__ __forceinline__ ushort f2bf(float f) {
  union { float f; unsigned u; } c; c.f = f;
  unsigned r = c.u + 0x7FFFu + ((c.u >> 16) & 1u);
  return (ushort)(r >> 16);
}

// x [N][IC][56][56] f32 -> xp [N][58][58][IC] bf16, halo rows/cols written as 0
// (fused halo zeroing: no separate 55MB memset needed)
__global__ void k_transpose(const float* __restrict__ x, ushort* __restrict__ xp) {
  __shared__ float tile[ICN*57];   // stride 57: conflict-free transpose read
  int h = blockIdx.x, n = blockIdx.y;          // h = padded row 0..57
  ushort* dst = xp + ((size_t)n*SPAT + (size_t)h*HP)*ICN;
  if (h == 0 || h == HP-1) {
    for (int e = threadIdx.x; e < HP*ICN/4; e += 256) ((us4*)dst)[e] = (us4){0,0,0,0};
    return;
  }
  const float* src = x + ((size_t)n*ICN*HSZ*WSZ) + (size_t)(h-1)*WSZ;
  for (int e = threadIdx.x; e < ICN*WSZ; e += 256) {
    int ic = e / WSZ, w = e - ic*WSZ;                 // w fastest -> coalesced read
    tile[ic*57 + w] = src[(size_t)ic*(HSZ*WSZ) + w];
  }
  __syncthreads();
  for (int e = threadIdx.x; e < ICN*HP; e += 256) {   // e = w*256+ic, w=0..57
    int w = e >> 8, ic = e & 255;
    dst[e] = (w == 0 || w == HP-1) ? (ushort)0 : f2bf(tile[ic*57 + (w-1)]);
  }
}

// COO scatter into dense fp32 W [oc][k], duplicates sum via atomicAdd
__global__ void k_scatter(const int* __restrict__ idx, const float* __restrict__ val,
                          float* __restrict__ wd, int nnz) {
  int i = blockIdx.x*256 + threadIdx.x;
  if (i >= nnz) return;
  int id = idx[i];
  int oc = id / (ICN*9);
  int rem = id - oc*(ICN*9);
  int ic = rem / 9;
  int k9 = rem - ic*9;                                // kh*3+kw
  atomicAdd(wd + (size_t)oc*KTOT + k9*ICN + ic, val[i]);
}

__global__ void k_convert(const float* __restrict__ wd, ushort* __restrict__ bm) {
  int i = (blockIdx.x*256 + threadIdx.x)*4;
  float4 v = *(const float4*)(wd + i);
  us4 o; o[0]=f2bf(v.x); o[1]=f2bf(v.y); o[2]=f2bf(v.z); o[3]=f2bf(v.w);
  *(us4*)(bm + i) = o;
}

// ---------------- 8-phase 256x256 implicit-GEMM (T2+T3+T4+T5) ----------------
// out[m][oc] = sum_k A[m][k]*B[oc][k].  BM=BN=256, BK=64, 512 thr = 8 waves
// (2M x 4N, 128x64 C each).  K-tile = 4 stage units {A-kh0,B-kh0,A-kh1,B-kh1},
// 16KB each (2 gload_lds/thread).  4 phases/tile: (kh,mh); per phase one unit
// of tile t+1 staged; vmcnt(4) at end of phases 1 & 3 (never 0 in main loop).
// LDS swizzle: physical quad p = q ^ ((row>>1)&3)  (2-way residual, ~free);
// gld_lds dest linear, source pre-swizzled; ds_read applies same XOR.

#define GLD(gsrc, ldst) __builtin_amdgcn_global_load_lds( \
    (const __attribute__((address_space(1))) void*)(gsrc), \
    (__attribute__((address_space(3))) void*)(ldst), 16, 0, 0)
#define BAR()  asm volatile("s_barrier" ::: "memory")
#define VMW4() asm volatile("s_waitcnt vmcnt(4)" ::: "memory")
#define VMW0() asm volatile("s_waitcnt vmcnt(0)" ::: "memory")

#define STAGE_A(T1, KH) do { \
    const int t4_ = (T1) >> 2; const int khh_ = t4_/3, khw_ = t4_ - khh_*3; \
    const int off_ = ((khh_*HP + khw_) << 8) + (((T1) & 3) << 6) + ((KH) << 5); \
    ushort* b_ = &Ab[(((T1)&1)*2 + (KH))*8192]; \
    GLD(xp + srcA0 + off_, b_ + ldsSlot0); \
    GLD(xp + srcA1 + off_, b_ + ldsSlot1); } while (0)

#define STAGE_B(T1, KH) do { \
    const int off_ = (T1)*64 + ((KH) << 5); \
    ushort* b_ = &Bb[(((T1)&1)*2 + (KH))*8192]; \
    GLD(bm + srcB0 + off_, b_ + ldsSlot0); \
    GLD(bm + srcB1 + off_, b_ + ldsSlot1); } while (0)

#define LOADB(KH, C) do { \
    const char* pb_ = (const char*)(Bb + ((C)*2+(KH))*8192) + bLane; \
    bv[0] = *(const bf16x8*)(pb_); \
    bv[1] = *(const bf16x8*)(pb_ + 1024); \
    bv[2] = *(const bf16x8*)(pb_ + 2048); \
    bv[3] = *(const bf16x8*)(pb_ + 3072); } while (0)

#define LOADA(KH, MH, C) do { \
    const char* pa_ = (const char*)(Ab + ((C)*2+(KH))*8192) + aLane + (MH)*4096; \
    av[0] = *(const bf16x8*)(pa_); \
    av[1] = *(const bf16x8*)(pa_ + 1024); \
    av[2] = *(const bf16x8*)(pa_ + 2048); \
    av[3] = *(const bf16x8*)(pa_ + 3072); } while (0)

#define MFMA16(MH) do { \
    _Pragma("unroll") \
    for (int f_ = 0; f_ < 4; ++f_) { \
      _Pragma("unroll") \
      for (int n_ = 0; n_ < 4; ++n_) \
        acc[(MH)*4+f_][n_] = __builtin_amdgcn_mfma_f32_16x16x32_bf16( \
            av[f_], bv[n_], acc[(MH)*4+f_][n_], 0, 0, 0); \
    } } while (0)

__global__ __launch_bounds__(512, 2) void k_gemm8(const ushort* __restrict__ xp,
                                                  const ushort* __restrict__ bm,
                                                  const float* __restrict__ bias,
                                                  float* __restrict__ out) {
  // [2 buf][2 khalf][256 rows][32 k] bf16 each => 64KB + 64KB = 128KB LDS
  __shared__ __align__(16) ushort Ab[2*2*256*32];
  __shared__ __align__(16) ushort Bb[2*2*256*32];

  const int tid = threadIdx.x;
  const int lam = tid & 63;
  const int wv  = tid >> 6;            // 0..7
  const int wr  = wv >> 2;             // 0..1  (M half)
  const int wc  = wv & 3;              // 0..3  (N quarter)
  const int la  = lam & 15;
  const int pq  = (lam >> 4) ^ ((la >> 1) & 3);      // read-side physical quad
  const int m0  = blockIdx.x * 256;

  // fragment read lane offsets (bytes within one 16KB khalf region)
  const int aLane = wr*8192 + la*64 + pq*16;
  const int bLane = wc*4096 + la*64 + pq*16;

  // staging: slot row r = (i*8+wv)*16 + (lam>>2), physical quad lam&3,
  // logical octet q = (lam&3) ^ ((lam>>3)&3)  (inverse of read swizzle)
  const int qs = (lam & 3) ^ ((lam >> 3) & 3);
  int srcA0, srcA1, srcB0, srcB1;
  const int ldsSlot0 = (0*8 + wv)*512;   // wave-uniform ushort offsets
  const int ldsSlot1 = (1*8 + wv)*512;
  {
    int r0 = (0*8 + wv)*16 + (lam >> 2);
    int r1 = (1*8 + wv)*16 + (lam >> 2);
    int m, n, rem, oh, ow;
    m = m0 + r0; n = m/3136; rem = m - n*3136; oh = rem/56; ow = rem - oh*56;
    srcA0 = (n*SPAT + oh*HP + ow)*ICN + qs*8;
    m = m0 + r1; n = m/3136; rem = m - n*3136; oh = rem/56; ow = rem - oh*56;
    srcA1 = (n*SPAT + oh*HP + ow)*ICN + qs*8;
    srcB0 = r0*KTOT + qs*8;
    srcB1 = r1*KTOT + qs*8;
  }

  f32x4 acc[8][4];
#pragma unroll
  for (int a = 0; a < 8; ++a)
#pragma unroll
    for (int b = 0; b < 4; ++b) acc[a][b] = (f32x4){0.f, 0.f, 0.f, 0.f};

  bf16x8 av[4], bv[4];

  // prologue: stage tile 0, keep its kh1 units in flight
  STAGE_A(0, 0); STAGE_B(0, 0); STAGE_A(0, 1); STAGE_B(0, 1);
  VMW4();
  BAR();

  for (int t = 0; t < NT-1; ++t) {
    const int c = t & 1;
    // phase 0: kh0, mh0  | stage A-kh0(t+1)
    LOADB(0, c); LOADA(0, 0, c);
    STAGE_A(t+1, 0);
    BAR();
    __builtin_amdgcn_s_setprio(1); MFMA16(0); __builtin_amdgcn_s_setprio(0);
    BAR();
    // phase 1: kh0, mh1  | stage B-kh0(t+1) | vmcnt(4): kh1(t) landed
    LOADA(0, 1, c);
    STAGE_B(t+1, 0);
    BAR();
    __builtin_amdgcn_s_setprio(1); MFMA16(1); __builtin_amdgcn_s_setprio(0);
    VMW4();
    BAR();
    // phase 2: kh1, mh0  | stage A-kh1(t+1)
    LOADB(1, c); LOADA(1, 0, c);
    STAGE_A(t+1, 1);
    BAR();
    __builtin_amdgcn_s_setprio(1); MFMA16(0); __builtin_amdgcn_s_setprio(0);
    BAR();
    // phase 3: kh1, mh1  | stage B-kh1(t+1) | vmcnt(4): kh0(t+1) landed
    LOADA(1, 1, c);
    STAGE_B(t+1, 1);
    BAR();
    __builtin_amdgcn_s_setprio(1); MFMA16(1); __builtin_amdgcn_s_setprio(0);
    VMW4();
    BAR();
  }

  // peeled last tile (t = NT-1, c = 1): no staging; drain kh1 before phase 2
  {
    const int c = (NT-1) & 1;
    LOADB(0, c); LOADA(0, 0, c);
    BAR();
    __builtin_amdgcn_s_setprio(1); MFMA16(0); __builtin_amdgcn_s_setprio(0);
    BAR();
    LOADA(0, 1, c);
    BAR();
    __builtin_amdgcn_s_setprio(1); MFMA16(1); __builtin_amdgcn_s_setprio(0);
    VMW0();
    BAR();
    LOADB(1, c); LOADA(1, 0, c);
    BAR();
    __builtin_amdgcn_s_setprio(1); MFMA16(0); __builtin_amdgcn_s_setprio(0);
    BAR();
    LOADA(1, 1, c);
    __builtin_amdgcn_s_setprio(1); MFMA16(1); __builtin_amdgcn_s_setprio(0);
  }

  // epilogue: lane l -> col(oc) = la, rows m = base + (l>>4)*4 + j
#pragma unroll
  for (int nn = 0; nn < 4; ++nn) {
    int oc = wc*64 + nn*16 + la;
    float bvs = bias[oc];
#pragma unroll
    for (int mf = 0; mf < 8; ++mf) {
      int m = m0 + wr*128 + mf*16 + ((lam >> 4) << 2);
      int n = m / 3136;
      int rem = m - n*3136;     // float4 never straddles n (3136 % 4 == 0)
      float4 o;
      o.x = acc[mf][nn][0] + bvs;
      o.y = acc[mf][nn][1] + bvs;
      o.z = acc[mf][nn][2] + bvs;
      o.w = acc[mf][nn][3] + bvs;
      *(float4*)(out + ((size_t)(n*OCN + oc))*3136 + rem) = o;
    }
  }
}

extern "C" void kernel_launch(void* const* d_in, const int* in_sizes, int n_in,
                              void* d_out, int out_size, void* d_ws, size_t ws_size,
                              hipStream_t stream) {
  const float* x    = (const float*)d_in[0];
  const float* wval = (const float*)d_in[1];
  const int*   widx = (const int*)d_in[2];
  const float* bias = (const float*)d_in[3];
  float* out = (float*)d_out;
  const int nnz = in_sizes[1];

  char* ws = (char*)d_ws;
  ushort* xp = (ushort*)ws;                               // 55.1 MB
  float*  wd = (float*)(ws + XP_BYTES);                   // 2.36 MB
  ushort* bm = (ushort*)(ws + XP_BYTES + WD_BYTES);       // 1.18 MB

  hipMemsetAsync(wd, 0, WD_BYTES, stream);
  k_transpose<<<dim3(HP, NBATCH), 256, 0, stream>>>(x, xp);
  k_scatter<<<dim3((nnz + 255)/256), 256, 0, stream>>>(widx, wval, wd, nnz);
  k_convert<<<dim3((OCN*KTOT)/(256*4)), 256, 0, stream>>>(wd, bm);
  k_gemm8<<<dim3(MTOT/256), 512, 0, stream>>>(xp, bm, bias, out);
}

// Round 4
// 192.274 us; speedup vs baseline: 1.3264x; 1.1803x over previous
//
#include <hip/hip_runtime.h>

typedef unsigned short ushort;
typedef __attribute__((ext_vector_type(8))) short bf16x8;
typedef __attribute__((ext_vector_type(4))) float f32x4;
typedef __attribute__((ext_vector_type(4))) ushort us4;

#define NBATCH 32
#define ICN 256
#define OCN 256
#define HSZ 56
#define WSZ 56
#define HP 58
#define SPAT (HP*HP)            /* 3364 */
#define KTOT 2304               /* 9*256, k = (kh*3+kw)*256 + ic */
#define MTOT (NBATCH*HSZ*WSZ)   /* 100352 */
#define NT   (KTOT/64)          /* 36 K-tiles of BK=64 */

#define XP_BYTES ((size_t)NBATCH*SPAT*ICN*2)   /* 55,115,776 */
#define WD_BYTES ((size_t)OCN*KTOT*4)          /* 2,359,296  */

__device__ __forceinline__ ushort f2bf(float f) {
  union { float f; unsigned u; } c; c.f = f;
  unsigned r = c.u + 0x7FFFu + ((c.u >> 16) & 1u);
  return (ushort)(r >> 16);
}

// x [N][IC][56][56] f32 -> xp [N][58][58][IC] bf16, halo rows/cols written as 0
__global__ void k_transpose(const float* __restrict__ x, ushort* __restrict__ xp) {
  __shared__ float tile[ICN*57];   // stride 57: conflict-free transpose read
  int h = blockIdx.x, n = blockIdx.y;          // h = padded row 0..57
  ushort* dst = xp + ((size_t)n*SPAT + (size_t)h*HP)*ICN;
  if (h == 0 || h == HP-1) {
    for (int e = threadIdx.x; e < HP*ICN/4; e += 256) ((us4*)dst)[e] = (us4){0,0,0,0};
    return;
  }
  const float* src = x + ((size_t)n*ICN*HSZ*WSZ) + (size_t)(h-1)*WSZ;
  for (int e = threadIdx.x; e < ICN*WSZ; e += 256) {
    int ic = e / WSZ, w = e - ic*WSZ;                 // w fastest -> coalesced read
    tile[ic*57 + w] = src[(size_t)ic*(HSZ*WSZ) + w];
  }
  __syncthreads();
  for (int e = threadIdx.x; e < ICN*HP; e += 256) {   // e = w*256+ic, w=0..57
    int w = e >> 8, ic = e & 255;
    dst[e] = (w == 0 || w == HP-1) ? (ushort)0 : f2bf(tile[ic*57 + (w-1)]);
  }
}

// COO scatter into dense fp32 W [oc][k], duplicates sum via atomicAdd
__global__ void k_scatter(const int* __restrict__ idx, const float* __restrict__ val,
                          float* __restrict__ wd, int nnz) {
  int i = blockIdx.x*256 + threadIdx.x;
  if (i >= nnz) return;
  int id = idx[i];
  int oc = id / (ICN*9);
  int rem = id - oc*(ICN*9);
  int ic = rem / 9;
  int k9 = rem - ic*9;                                // kh*3+kw
  atomicAdd(wd + (size_t)oc*KTOT + k9*ICN + ic, val[i]);
}

__global__ void k_convert(const float* __restrict__ wd, ushort* __restrict__ bm) {
  int i = (blockIdx.x*256 + threadIdx.x)*4;
  float4 v = *(const float4*)(wd + i);
  us4 o; o[0]=f2bf(v.x); o[1]=f2bf(v.y); o[2]=f2bf(v.z); o[3]=f2bf(v.w);
  *(us4*)(bm + i) = o;
}

// ---------------- 8-phase 256x256 implicit-GEMM (T2+T3+T4+T5) ----------------
// out[m][oc] = sum_k A[m][k]*B[oc][k].  BM=BN=256, BK=64, 512 thr = 8 waves
// (2M x 4N, 128x64 C each).  Fragment loads are INLINE-ASM ds_read_b128 so the
// waitcnt pass can't see a gld_lds->ds_read hazard and insert vmcnt(0) drains
// (rule #18 discipline: explicit lgkmcnt(0) + sched_barrier(0) before MFMA).

#define GLD(gsrc, ldst) __builtin_amdgcn_global_load_lds( \
    (const __attribute__((address_space(1))) void*)(gsrc), \
    (__attribute__((address_space(3))) void*)(ldst), 16, 0, 0)
#define BAR()  asm volatile("s_barrier" ::: "memory")
#define VMW4() asm volatile("s_waitcnt vmcnt(4)" ::: "memory")
#define VMW0() asm volatile("s_waitcnt vmcnt(0)" ::: "memory")
#define LGKM0SB() do { asm volatile("s_waitcnt lgkmcnt(0)" ::: "memory"); \
                       __builtin_amdgcn_sched_barrier(0); } while (0)

#define STAGE_A(T1, KH) do { \
    const int t4_ = (T1) >> 2; const int khh_ = t4_/3, khw_ = t4_ - khh_*3; \
    const int off_ = ((khh_*HP + khw_) << 8) + (((T1) & 3) << 6) + ((KH) << 5); \
    ushort* b_ = &Ab[(((T1)&1)*2 + (KH))*8192]; \
    GLD(xp + srcA0 + off_, b_ + ldsSlot0); \
    GLD(xp + srcA1 + off_, b_ + ldsSlot1); } while (0)

#define STAGE_B(T1, KH) do { \
    const int off_ = (T1)*64 + ((KH) << 5); \
    ushort* b_ = &Bb[(((T1)&1)*2 + (KH))*8192]; \
    GLD(bm + srcB0 + off_, b_ + ldsSlot0); \
    GLD(bm + srcB1 + off_, b_ + ldsSlot1); } while (0)

// Inline-asm fragment loads: 4 x ds_read_b128 off one base VGPR.
#define LOADB(KH, C) do { \
    unsigned a_ = BbB + (unsigned)(((C)*2+(KH))*16384) + bLane; \
    asm volatile("ds_read_b128 %0, %4 offset:0\n\t" \
                 "ds_read_b128 %1, %4 offset:1024\n\t" \
                 "ds_read_b128 %2, %4 offset:2048\n\t" \
                 "ds_read_b128 %3, %4 offset:3072" \
                 : "=&v"(bv[0]), "=&v"(bv[1]), "=&v"(bv[2]), "=&v"(bv[3]) \
                 : "v"(a_)); } while (0)

#define LOADA(KH, MH, C) do { \
    unsigned a_ = AbB + (unsigned)(((C)*2+(KH))*16384 + (MH)*4096) + aLane; \
    asm volatile("ds_read_b128 %0, %4 offset:0\n\t" \
                 "ds_read_b128 %1, %4 offset:1024\n\t" \
                 "ds_read_b128 %2, %4 offset:2048\n\t" \
                 "ds_read_b128 %3, %4 offset:3072" \
                 : "=&v"(av[0]), "=&v"(av[1]), "=&v"(av[2]), "=&v"(av[3]) \
                 : "v"(a_)); } while (0)

#define MFMA16(MH) do { \
    _Pragma("unroll") \
    for (int f_ = 0; f_ < 4; ++f_) { \
      _Pragma("unroll") \
      for (int n_ = 0; n_ < 4; ++n_) \
        acc[(MH)*4+f_][n_] = __builtin_amdgcn_mfma_f32_16x16x32_bf16( \
            av[f_], bv[n_], acc[(MH)*4+f_][n_], 0, 0, 0); \
    } } while (0)

__global__ __launch_bounds__(512, 2) void k_gemm8(const ushort* __restrict__ xp,
                                                  const ushort* __restrict__ bm,
                                                  const float* __restrict__ bias,
                                                  float* __restrict__ out) {
  // [2 buf][2 khalf][256 rows][32 k] bf16 each => 64KB + 64KB = 128KB LDS
  __shared__ __align__(16) ushort Ab[2*2*256*32];
  __shared__ __align__(16) ushort Bb[2*2*256*32];

  const int tid = threadIdx.x;
  const int lam = tid & 63;
  const int wv  = tid >> 6;            // 0..7
  const int wr  = wv >> 2;             // 0..1  (M half)
  const int wc  = wv & 3;              // 0..3  (N quarter)
  const int la  = lam & 15;
  const int pq  = (lam >> 4) ^ ((la >> 1) & 3);      // read-side physical quad
  const int m0  = blockIdx.x * 256;

  const unsigned AbB = (unsigned)(uintptr_t)(__attribute__((address_space(3))) char*)Ab;
  const unsigned BbB = (unsigned)(uintptr_t)(__attribute__((address_space(3))) char*)Bb;

  // fragment read lane offsets (bytes within one 16KB khalf region)
  const unsigned aLane = wr*8192 + la*64 + pq*16;
  const unsigned bLane = wc*4096 + la*64 + pq*16;

  // staging: slot row r = (i*8+wv)*16 + (lam>>2), physical quad lam&3,
  // logical octet q = (lam&3) ^ ((lam>>3)&3)  (inverse of read swizzle)
  const int qs = (lam & 3) ^ ((lam >> 3) & 3);
  int srcA0, srcA1, srcB0, srcB1;
  const int ldsSlot0 = (0*8 + wv)*512;   // wave-uniform ushort offsets
  const int ldsSlot1 = (1*8 + wv)*512;
  {
    int r0 = (0*8 + wv)*16 + (lam >> 2);
    int r1 = (1*8 + wv)*16 + (lam >> 2);
    int m, n, rem, oh, ow;
    m = m0 + r0; n = m/3136; rem = m - n*3136; oh = rem/56; ow = rem - oh*56;
    srcA0 = (n*SPAT + oh*HP + ow)*ICN + qs*8;
    m = m0 + r1; n = m/3136; rem = m - n*3136; oh = rem/56; ow = rem - oh*56;
    srcA1 = (n*SPAT + oh*HP + ow)*ICN + qs*8;
    srcB0 = r0*KTOT + qs*8;
    srcB1 = r1*KTOT + qs*8;
  }

  f32x4 acc[8][4];
#pragma unroll
  for (int a = 0; a < 8; ++a)
#pragma unroll
    for (int b = 0; b < 4; ++b) acc[a][b] = (f32x4){0.f, 0.f, 0.f, 0.f};

  bf16x8 av[4], bv[4];

  // prologue: stage tile 0, keep its kh1 units in flight
  STAGE_A(0, 0); STAGE_B(0, 0); STAGE_A(0, 1); STAGE_B(0, 1);
  VMW4();
  BAR();

  for (int t = 0; t < NT-1; ++t) {
    const int c = t & 1;
    // phase 0: kh0, mh0  | stage A-kh0(t+1)
    LOADB(0, c); LOADA(0, 0, c);
    STAGE_A(t+1, 0);
    BAR();
    LGKM0SB();
    __builtin_amdgcn_s_setprio(1); MFMA16(0); __builtin_amdgcn_s_setprio(0);
    BAR();
    // phase 1: kh0, mh1  | stage B-kh0(t+1) | vmcnt(4): kh1(t) landed
    LOADA(0, 1, c);
    STAGE_B(t+1, 0);
    BAR();
    LGKM0SB();
    __builtin_amdgcn_s_setprio(1); MFMA16(1); __builtin_amdgcn_s_setprio(0);
    VMW4();
    BAR();
    // phase 2: kh1, mh0  | stage A-kh1(t+1)
    LOADB(1, c); LOADA(1, 0, c);
    STAGE_A(t+1, 1);
    BAR();
    LGKM0SB();
    __builtin_amdgcn_s_setprio(1); MFMA16(0); __builtin_amdgcn_s_setprio(0);
    BAR();
    // phase 3: kh1, mh1  | stage B-kh1(t+1) | vmcnt(4): kh0(t+1) landed
    LOADA(1, 1, c);
    STAGE_B(t+1, 1);
    BAR();
    LGKM0SB();
    __builtin_amdgcn_s_setprio(1); MFMA16(1); __builtin_amdgcn_s_setprio(0);
    VMW4();
    BAR();
  }

  // peeled last tile (t = NT-1): no staging; drain before kh1 reads
  {
    const int c = (NT-1) & 1;
    LOADB(0, c); LOADA(0, 0, c);
    BAR();
    LGKM0SB();
    __builtin_amdgcn_s_setprio(1); MFMA16(0); __builtin_amdgcn_s_setprio(0);
    BAR();
    LOADA(0, 1, c);
    BAR();
    LGKM0SB();
    __builtin_amdgcn_s_setprio(1); MFMA16(1); __builtin_amdgcn_s_setprio(0);
    VMW0();
    BAR();
    LOADB(1, c); LOADA(1, 0, c);
    BAR();
    LGKM0SB();
    __builtin_amdgcn_s_setprio(1); MFMA16(0); __builtin_amdgcn_s_setprio(0);
    BAR();
    LOADA(1, 1, c);
    LGKM0SB();
    __builtin_amdgcn_s_setprio(1); MFMA16(1); __builtin_amdgcn_s_setprio(0);
  }

  // epilogue: lane l -> col(oc) = la, rows m = base + (l>>4)*4 + j
#pragma unroll
  for (int nn = 0; nn < 4; ++nn) {
    int oc = wc*64 + nn*16 + la;
    float bvs = bias[oc];
#pragma unroll
    for (int mf = 0; mf < 8; ++mf) {
      int m = m0 + wr*128 + mf*16 + ((lam >> 4) << 2);
      int n = m / 3136;
      int rem = m - n*3136;     // float4 never straddles n (3136 % 4 == 0)
      float4 o;
      o.x = acc[mf][nn][0] + bvs;
      o.y = acc[mf][nn][1] + bvs;
      o.z = acc[mf][nn][2] + bvs;
      o.w = acc[mf][nn][3] + bvs;
      *(float4*)(out + ((size_t)(n*OCN + oc))*3136 + rem) = o;
    }
  }
}

extern "C" void kernel_launch(void* const* d_in, const int* in_sizes, int n_in,
                              void* d_out, int out_size, void* d_ws, size_t ws_size,
                              hipStream_t stream) {
  const float* x    = (const float*)d_in[0];
  const float* wval = (const float*)d_in[1];
  const int*   widx = (const int*)d_in[2];
  const float* bias = (const float*)d_in[3];
  float* out = (float*)d_out;
  const int nnz = in_sizes[1];

  char* ws = (char*)d_ws;
  ushort* xp = (ushort*)ws;                               // 55.1 MB
  float*  wd = (float*)(ws + XP_BYTES);                   // 2.36 MB
  ushort* bm = (ushort*)(ws + XP_BYTES + WD_BYTES);       // 1.18 MB

  hipMemsetAsync(wd, 0, WD_BYTES, stream);
  k_transpose<<<dim3(HP, NBATCH), 256, 0, stream>>>(x, xp);
  k_scatter<<<dim3((nnz + 255)/256), 256, 0, stream>>>(widx, wval, wd, nnz);
  k_convert<<<dim3((OCN*KTOT)/(256*4)), 256, 0, stream>>>(wd, bm);
  k_gemm8<<<dim3(MTOT/256), 512, 0, stream>>>(xp, bm, bias, out);
}